// Round 4
// baseline (372.882 us; speedup 1.0000x reference)
//
#include <hip/hip_runtime.h>
#include <math.h>

#define NB    16
#define CIN   64
#define COUT  64
#define NN    16384
#define HH    8192
#define MODES 2048
#define TEMBD 512

// XOR bank swizzle: bijection on [0,8192); makes stride-32 and contiguous-32
// per-thread LDS access patterns conflict-free without padding.
__device__ __forceinline__ int swz(int e) { return e ^ ((e >> 5) & 31); }
__device__ __forceinline__ int rev13(int x) { return (int)(__brev((unsigned)x) >> 19); }

__global__ void init_tw_k(float2* __restrict__ tw8, float2* __restrict__ tw16) {
  int j = blockIdx.x * blockDim.x + threadIdx.x;
  if (j < 4096) {
    double a = (2.0 * 3.14159265358979323846 / 8192.0) * (double)j;
    tw8[j] = make_float2((float)cos(a), (float)sin(a));
  }
  if (j < 2048) {
    double a = (2.0 * 3.14159265358979323846 / 16384.0) * (double)j;
    tw16[j] = make_float2((float)cos(a), (float)sin(a));
  }
}

// In-register DIF pass: elements e_j = base + j*S, stages lh = LH_HI down.
template<int J, int S, int LH_HI>
__device__ __forceinline__ void pass_dif(float* zr, float* zi, int pbase,
                                         const float2* __restrict__ tw) {
  int lh = LH_HI;
#pragma unroll
  for (int half = J / 2; half >= 1; half >>= 1, --lh) {
#pragma unroll
    for (int blk = 0; blk < J; blk += 2 * half) {
#pragma unroll
      for (int q = 0; q < half; ++q) {
        const int j0 = blk + q, j1 = j0 + half;
        const float2 w = tw[(pbase + q * S) << (12 - lh)];
        const float ur = zr[j0], ui = zi[j0];
        const float vr = zr[j1], vi = zi[j1];
        zr[j0] = ur + vr; zi[j0] = ui + vi;
        const float br = ur - vr, bi = ui - vi;
        zr[j1] = br * w.x + bi * w.y;   // *(c - i s)
        zi[j1] = bi * w.x - br * w.y;
      }
    }
  }
}

// In-register DIT pass (e^{+i}): stages lh = LH_LO up.
template<int J, int S, int LH_LO>
__device__ __forceinline__ void pass_dit(float* zr, float* zi, int pbase,
                                         const float2* __restrict__ tw) {
  int lh = LH_LO;
#pragma unroll
  for (int half = 1; half <= J / 2; half <<= 1, ++lh) {
#pragma unroll
    for (int blk = 0; blk < J; blk += 2 * half) {
#pragma unroll
      for (int q = 0; q < half; ++q) {
        const int j0 = blk + q, j1 = j0 + half;
        const float2 w = tw[(pbase + q * S) << (12 - lh)];
        const float vr = zr[j1], vi = zi[j1];
        const float tr = vr * w.x - vi * w.y;  // *(c + i s)
        const float ti = vr * w.y + vi * w.x;
        const float ur = zr[j0], ui = zi[j0];
        zr[j0] = ur + tr; zi[j0] = ui + ti;
        zr[j1] = ur - tr; zi[j1] = ui - ti;
      }
    }
  }
}

// Forward: one 512-thread block per (b, c_in) row; 16 waves/CU (2 blocks x 8 waves).
__global__ __launch_bounds__(512) void fwd_fft_k(
    const float* __restrict__ x, const float* __restrict__ temb,
    const float* __restrict__ dw, const float* __restrict__ db,
    const float2* __restrict__ tw8, const float2* __restrict__ tw16,
    float2* __restrict__ xm)
{
  __shared__ float re[HH];
  __shared__ float im[HH];
  const int row = blockIdx.x;          // b*64 + ci
  const int b = row >> 6, ci = row & 63;
  const int tid = threadIdx.x;

  // t = silu(temb[b]) . dw[ci] + db[ci]  (one element per thread)
  {
    float v = temb[b * TEMBD + tid];
    float part = v * dw[ci * TEMBD + tid] / (1.f + __expf(-v));
    for (int off = 32; off > 0; off >>= 1) part += __shfl_down(part, off, 64);
    if ((tid & 63) == 0) re[tid >> 6] = part;
  }
  __syncthreads();
  const float tval = re[0] + re[1] + re[2] + re[3] +
                     re[4] + re[5] + re[6] + re[7] + db[ci];
  __syncthreads();

  float zr[32], zi[32];

  // P1: global packed z[m]=x[2m]+i x[2m+1] -> regs, stages lh=12..9, -> LDS
  const float2* xr = (const float2*)(x + (size_t)row * NN);
  {
    const int i0 = tid;
#pragma unroll
    for (int j = 0; j < 16; ++j) {
      float2 v = xr[i0 + j * 512];
      zr[j] = v.x; zi[j] = v.y;
    }
    pass_dif<16, 512, 12>(zr, zi, i0, tw8);
#pragma unroll
    for (int j = 0; j < 16; ++j) {
      const int e = swz(i0 + j * 512);
      re[e] = zr[j]; im[e] = zi[j];
    }
  }
  __syncthreads();

  // P2: stride-32 groups, stages lh=8..5
  {
    const int r = tid & 31;
    const int base = (tid >> 5) * 512 + r;
#pragma unroll
    for (int j = 0; j < 16; ++j) {
      const int e = swz(base + j * 32);
      zr[j] = re[e]; zi[j] = im[e];
    }
    pass_dif<16, 32, 8>(zr, zi, r, tw8);
#pragma unroll
    for (int j = 0; j < 16; ++j) {
      const int e = swz(base + j * 32);
      re[e] = zr[j]; im[e] = zi[j];
    }
  }
  __syncthreads();

  // P3: contiguous-32 groups, stages lh=4..0 (first 256 threads)
  if (tid < 256) {
    const int base = tid * 32;
#pragma unroll
    for (int j = 0; j < 32; ++j) {
      const int e = swz(base + j);
      zr[j] = re[e]; zi[j] = im[e];
    }
    pass_dif<32, 1, 4>(zr, zi, 0, tw8);
#pragma unroll
    for (int j = 0; j < 32; ++j) {
      const int e = swz(base + j);
      re[e] = zr[j]; im[e] = zi[j];
    }
  }
  __syncthreads();

  // unpack X[k] = 0.5(A+conj(B)) - 0.5 i e^{-2pi i k/N} (A-conj(B))
  float2* xrow = xm + (size_t)row * MODES;
  for (int k = tid; k < MODES; k += 512) {
    const int ka = swz(rev13(k));
    const int kb = swz(rev13((HH - k) & (HH - 1)));
    float Ar = re[ka], Ai = im[ka];
    float Br = re[kb], Bi = -im[kb];
    float Sr = 0.5f * (Ar + Br), Si = 0.5f * (Ai + Bi);
    float Dr = 0.5f * (Ar - Br), Di = 0.5f * (Ai - Bi);
    float2 wv = tw16[k];
    float c = wv.x, s = wv.y;
    float Xr = Sr - s * Dr + c * Di;
    float Xi = Si - s * Di - c * Dr;
    xrow[k] = make_float2(Xr + tval, Xi);
  }
}

// out_m[b,o,m] = sum_i xm[b,i,m] * (wr[i,o,m] + i wi[i,o,m])
// Block = 64-mode tile x 4 o; thread owns ALL 16 b accumulators => w read
// exactly once from HBM. xm staged per 4-i chunk in 32 KiB LDS; w and xm
// global loads double-buffered one chunk ahead in registers.
#define IC 4
__global__ __launch_bounds__(256) void spec_mul_k(
    const float2* __restrict__ xm, const float* __restrict__ wr,
    const float* __restrict__ wi, float2* __restrict__ om)
{
  __shared__ float2 xs[16 * IC * 64];   // [b][ii][m] 32 KiB
  const int tid = threadIdx.x;
  const int m = tid & 63;
  const int o = blockIdx.y * 4 + (tid >> 6);
  const int m0 = blockIdx.x * 64;

  float2 acc[NB];
#pragma unroll
  for (int bb = 0; bb < NB; ++bb) acc[bb] = make_float2(0.f, 0.f);

  float4 xb[2][8];
  float wrb[2][IC], wib[2][IC];

#define LOAD_CHUNK(c, s)                                                      \
  {                                                                           \
    const int i0_ = (c) * IC;                                                 \
    _Pragma("unroll")                                                         \
    for (int k = 0; k < 8; ++k) {                                             \
      const int f = k * 256 + tid;                                            \
      const int bb_ = f >> 7, ii_ = (f >> 5) & 3, mq_ = f & 31;               \
      const float4* gp = (const float4*)(xm +                                 \
          ((size_t)(bb_ * CIN + i0_ + ii_)) * MODES + m0);                    \
      xb[s][k] = gp[mq_];                                                     \
    }                                                                         \
    _Pragma("unroll")                                                         \
    for (int ii = 0; ii < IC; ++ii) {                                         \
      const size_t widx = ((size_t)((i0_ + ii) * COUT + o)) * MODES + m0 + m; \
      wrb[s][ii] = wr[widx]; wib[s][ii] = wi[widx];                           \
    }                                                                         \
  }

  LOAD_CHUNK(0, 0)

  for (int c = 0; c < CIN / IC; ++c) {
    const int s = c & 1;
    if (c) __syncthreads();
#pragma unroll
    for (int k = 0; k < 8; ++k) {
      ((float4*)xs)[k * 256 + tid] = xb[s][k];
    }
    __syncthreads();
    if (c + 1 < CIN / IC) LOAD_CHUNK(c + 1, s ^ 1)
#pragma unroll
    for (int ii = 0; ii < IC; ++ii) {
      const float wrv = wrb[s][ii], wiv = wib[s][ii];
#pragma unroll
      for (int bb = 0; bb < NB; ++bb) {
        float2 xv = xs[(bb * IC + ii) * 64 + m];
        acc[bb].x += xv.x * wrv - xv.y * wiv;
        acc[bb].y += xv.x * wiv + xv.y * wrv;
      }
    }
  }

#pragma unroll
  for (int bb = 0; bb < NB; ++bb)
    om[((size_t)(bb * COUT + o)) * MODES + m0 + m] = acc[bb];
}

// Inverse: one 512-thread block per (b, c_out) row.
__global__ __launch_bounds__(512) void inv_fft_k(
    const float2* __restrict__ om, const float2* __restrict__ tw8,
    const float2* __restrict__ tw16, float* __restrict__ out)
{
  __shared__ float re[HH];
  __shared__ float im[HH];
  const int row = blockIdx.x;   // b*64 + o
  const int tid = threadIdx.x;

  for (int q = tid; q < HH; q += 512) { re[q] = 0.f; im[q] = 0.f; }
  __syncthreads();

  const float2* grow = om + (size_t)row * MODES;
  for (int k = tid; k < MODES; k += 512) {
    float2 g = grow[k];
    if (k == 0) {
      float v = 0.5f * g.x;        // Zb[0] = 0.5*Re(G0)*(1+i)
      re[0] = v; im[0] = v;
    } else {
      float2 wv = tw16[k];
      float Pr = 0.5f * g.x, Pi = 0.5f * g.y;
      float c = wv.x, s = wv.y;
      float sr = -(c * Pi + s * Pr);
      float si =  (c * Pr - s * Pi);
      int ka = swz(rev13(k));
      int kb = swz(rev13(HH - k));
      re[ka] = Pr + sr; im[ka] = Pi + si;
      re[kb] = Pr - sr; im[kb] = -(Pi - si);
    }
  }
  __syncthreads();

  float zr[32], zi[32];

  // P1: contiguous-32 groups, stages lh=0..4 (first 256 threads)
  if (tid < 256) {
    const int base = tid * 32;
#pragma unroll
    for (int j = 0; j < 32; ++j) {
      const int e = swz(base + j);
      zr[j] = re[e]; zi[j] = im[e];
    }
    pass_dit<32, 1, 0>(zr, zi, 0, tw8);
#pragma unroll
    for (int j = 0; j < 32; ++j) {
      const int e = swz(base + j);
      re[e] = zr[j]; im[e] = zi[j];
    }
  }
  __syncthreads();

  // P2: stride-32 groups, stages lh=5..8
  {
    const int r = tid & 31;
    const int base = (tid >> 5) * 512 + r;
#pragma unroll
    for (int j = 0; j < 16; ++j) {
      const int e = swz(base + j * 32);
      zr[j] = re[e]; zi[j] = im[e];
    }
    pass_dit<16, 32, 5>(zr, zi, r, tw8);
#pragma unroll
    for (int j = 0; j < 16; ++j) {
      const int e = swz(base + j * 32);
      re[e] = zr[j]; im[e] = zi[j];
    }
  }
  __syncthreads();

  // P3: stride-512 groups, stages lh=9..12; write x[2m],x[2m+1] as float2
  {
    float2* orow = (float2*)(out + (size_t)row * NN);
    const float sc = 1.0f / 8192.0f;
    const int i0 = tid;
#pragma unroll
    for (int j = 0; j < 16; ++j) {
      const int e = swz(i0 + j * 512);
      zr[j] = re[e]; zi[j] = im[e];
    }
    pass_dit<16, 512, 9>(zr, zi, i0, tw8);
#pragma unroll
    for (int j = 0; j < 16; ++j) {
      orow[i0 + j * 512] = make_float2(zr[j] * sc, zi[j] * sc);
    }
  }
}

extern "C" void kernel_launch(void* const* d_in, const int* in_sizes, int n_in,
                              void* d_out, int out_size, void* d_ws, size_t ws_size,
                              hipStream_t stream) {
  const float* x    = (const float*)d_in[0];
  const float* temb = (const float*)d_in[1];
  const float* wr   = (const float*)d_in[2];
  const float* wi   = (const float*)d_in[3];
  const float* dw   = (const float*)d_in[4];
  const float* db   = (const float*)d_in[5];
  float* out = (float*)d_out;

  char* ws = (char*)d_ws;
  float2* tw8  = (float2*)ws;                               // 32 KiB
  float2* tw16 = (float2*)(ws + 32768);                     // 16 KiB
  float2* xm   = (float2*)(ws + 65536);                     // 16 MiB
  float2* om   = (float2*)(ws + 65536 + (size_t)16777216);  // 16 MiB

  hipLaunchKernelGGL(init_tw_k, dim3(16), dim3(256), 0, stream, tw8, tw16);
  hipLaunchKernelGGL(fwd_fft_k, dim3(NB * CIN), dim3(512), 0, stream,
                     x, temb, dw, db, tw8, tw16, xm);
  hipLaunchKernelGGL(spec_mul_k, dim3(MODES / 64, COUT / 4), dim3(256), 0, stream,
                     xm, wr, wi, om);
  hipLaunchKernelGGL(inv_fft_k, dim3(NB * COUT), dim3(512), 0, stream,
                     om, tw8, tw16, out);
}